// Round 13
// baseline (422.110 us; speedup 1.0000x reference)
//
#include <hip/hip_runtime.h>

typedef unsigned short u16;
typedef __attribute__((ext_vector_type(8))) short bf16x8;
typedef __attribute__((ext_vector_type(4))) float f32x4;
typedef __attribute__((ext_vector_type(8))) unsigned short u16x8;
typedef __attribute__((ext_vector_type(4))) unsigned short u16x4;

__device__ __forceinline__ u16 f2bf(float f){
  unsigned int u = __builtin_bit_cast(unsigned int, f);
  u += 0x7FFFu + ((u >> 16) & 1u);
  return (u16)(u >> 16);
}
__device__ __forceinline__ float bf2f(u16 h){
  unsigned int u = ((unsigned int)h) << 16;
  return __builtin_bit_cast(float, u);
}

__device__ __forceinline__ void load16(const u16* g, u16* s){
  __builtin_amdgcn_global_load_lds((const __attribute__((address_space(1))) unsigned int*)g,
                                   (__attribute__((address_space(3))) unsigned int*)s,
                                   16, 0, 0);
}

// From R: S = 0.5(A-A^T). Sbf = bf16(S); Dbf = bf16((c+1)(cI - S)), c=1.000001
__global__ __launch_bounds__(256) void build_s(const float* __restrict__ R, u16* __restrict__ Sbf,
                                               u16* __restrict__ Dbf){
  int idx = blockIdx.x * 256 + threadIdx.x;
  int b = idx >> 18;
  int i = (idx >> 9) & 511;
  int j = idx & 511;
  float a  = R[idx];
  float at = R[(b << 18) + (j << 9) + i];
  float s = 0.5f * (a - at);
  Sbf[idx] = f2bf(s);
  Dbf[idx] = f2bf((i == j ? 2.000003f : 0.0f) - 2.000001f * s);
}

// Wt[b][i][j] = W[b*512 + j][i]  (bf16), i in [0,4096), j in [0,512)
__global__ __launch_bounds__(256) void transpose_w(const float* __restrict__ W, u16* __restrict__ Wt){
  const int b = blockIdx.z;
  const int i0 = blockIdx.x << 5;
  const int j0 = blockIdx.y << 5;
  __shared__ float tile[32][33];
  const int t = threadIdx.x;
  const int r = t >> 3, c = (t & 7) << 2;
  float4 v = *(const float4*)&W[(size_t)((b << 9) + j0 + r) * 4096 + i0 + c];
  tile[r][c+0] = v.x; tile[r][c+1] = v.y; tile[r][c+2] = v.z; tile[r][c+3] = v.w;
  __syncthreads();
  u16x4 o = { f2bf(tile[c+0][r]), f2bf(tile[c+1][r]), f2bf(tile[c+2][r]), f2bf(tile[c+3][r]) };
  *(u16x4*)&Wt[((size_t)b << 21) + (size_t)(i0 + r) * 512 + j0 + c] = o;
}

// 64x64-tile bt-form bf16 MFMA gemm for the small NS steps: grid (N/64, M/64, 8)
// = 512 blocks (2 blocks/CU). 4 waves (2Mx2N), each 32x32 (2x2 16x16x32 frags).
// Single-buffered LDS, __syncthreads staging (deterministic class), 4-slot XOR
// swizzle: LDS[r][slot] = G[r][slot ^ (r&3)], read slot ((l>>4)^l)&3.
// EPI 2:  bf16 C = acc
// EPI 3:  bf16 C = 2*diag - acc
// EPI 9:  bf16 C = acc - diag
// EPI 11: p = acc + c^2*diag (f32): Cout(width1024)=[bf16(p)|bf16(p-ph)];
//         x1 = bf16(2b*diag - b^2*p) -> aux (width 512) and aux2 (width 1024, dup)
template<int EPI>
__global__ __launch_bounds__(256) void gemm_ns(const u16* __restrict__ A, const u16* __restrict__ B,
                                               void* __restrict__ Cout, void* __restrict__ aux,
                                               void* __restrict__ aux2,
                                               int M, int N, int K){
  const int bz = blockIdx.z;
  const char* Ab = (const char*)(A + (size_t)bz * M * K);
  const char* Bb = (const char*)(B + (size_t)bz * N * K);
  const int m0 = blockIdx.y << 6, n0 = blockIdx.x << 6;
  __shared__ __align__(16) char As[4096];
  __shared__ __align__(16) char Bs[4096];
  const int t = threadIdx.x;
  const int w = t >> 6, l = t & 63;
  const int wm = w >> 1, wn = w & 1;
  const size_t Kb = (size_t)K << 1;
  const int sR = t >> 2;
  const int sK = ((t ^ (t >> 2)) & 3) << 4;
  const int kq = (((l >> 4) ^ l) & 3) << 4;
  const int aRd = ((wm << 5) + (l & 15)) * 64 + kq;
  const int bRd = ((wn << 5) + (l & 15)) * 64 + kq;
  f32x4 acc[2][2] = {};
  for (int k0 = 0; k0 < K; k0 += 32){
    const size_t kb = (size_t)k0 << 1;
    load16((const u16*)(Ab + (size_t)(m0 + sR) * Kb + kb + sK), (u16*)(As + t * 16));
    load16((const u16*)(Bb + (size_t)(n0 + sR) * Kb + kb + sK), (u16*)(Bs + t * 16));
    __syncthreads();
    bf16x8 aF[2], bF[2];
#pragma unroll
    for (int mf = 0; mf < 2; ++mf) aF[mf] = *(const bf16x8*)(As + aRd + (mf << 10));
#pragma unroll
    for (int nf = 0; nf < 2; ++nf) bF[nf] = *(const bf16x8*)(Bs + bRd + (nf << 10));
#pragma unroll
    for (int mf = 0; mf < 2; ++mf)
#pragma unroll
      for (int nf = 0; nf < 2; ++nf)
        acc[mf][nf] = __builtin_amdgcn_mfma_f32_16x16x32_bf16(aF[mf], bF[nf], acc[mf][nf], 0, 0, 0);
    __syncthreads();
  }
#pragma unroll
  for (int mf = 0; mf < 2; ++mf){
#pragma unroll
    for (int nf = 0; nf < 2; ++nf){
      const int col = n0 + (wn << 5) + (nf << 4) + (l & 15);
#pragma unroll
      for (int q = 0; q < 4; ++q){
        const int row = m0 + (wm << 5) + (mf << 4) + ((l >> 4) << 2) + q;
        float v = acc[mf][nf][q];
        size_t gi = ((size_t)bz * M + row) * N + col;
        size_t g2 = (((size_t)bz * M + row) << 10) + col;
        if (EPI == 2){
          ((u16*)Cout)[gi] = f2bf(v);
        } else if (EPI == 3){
          ((u16*)Cout)[gi] = f2bf((row == col ? 2.0f : 0.0f) - v);
        } else if (EPI == 9){
          ((u16*)Cout)[gi] = f2bf(v - (row == col ? 1.0f : 0.0f));
        } else {  // EPI 11
          float p = v + (row == col ? 1.000002f : 0.0f);
          u16 ph = f2bf(p);
          ((u16*)Cout)[g2] = ph;
          ((u16*)Cout)[g2 + 512] = f2bf(p - bf2f(ph));
          const float beta = 0.8264463f;
          u16 x1 = f2bf((row == col ? 2.0f * beta : 0.0f) - beta * beta * p);
          ((u16*)aux)[gi] = x1;
          ((u16*)aux2)[g2] = x1;
          ((u16*)aux2)[g2 + 512] = x1;
        }
      }
    }
  }
}

// 256x256-tile bt-form bf16 MFMA gemm — ROUND-9 VERSION VERBATIM (replay-stable).
// Used only for the filt GEMM now (EPI 2). See round-9/10 comments for the
// structure and the occupancy lesson.
template<int EPI>
__global__ __launch_bounds__(512, 2) void gemm256(const u16* __restrict__ A, const u16* __restrict__ B,
                                                  void* __restrict__ Cout, const float* __restrict__ aux,
                                                  int M, int N, int K){
  __shared__ __align__(16) char lds[131072];
  const int bz = blockIdx.z;
  const char* Ab = (const char*)(A + (size_t)bz * M * K);
  const char* Bb = (const char*)(B + (size_t)bz * N * K);
  const int NB = N >> 8;
  const int nwg = gridDim.x;
  const int bid = blockIdx.x;
  const int swzb = (bid & 7) * (nwg >> 3) + (bid >> 3);   // nwg % 8 == 0
  const int m0 = (swzb / NB) << 8;
  const int n0 = (swzb % NB) << 8;
  const int tid = threadIdx.x;
  const int w = tid >> 6, l = tid & 63;
  const int wm = w >> 2, wn = w & 3;
  const size_t Kb = (size_t)K << 1;
  const int NT = K >> 6;
  const int sRow = tid >> 3;
  const int sCol = ((tid & 7) << 4) ^ ((sRow & 7) << 4);
  const int sDst = tid << 4;
  const char* aS = Ab + (size_t)(m0 + sRow) * Kb + sCol;
  const char* bS = Bb + (size_t)(n0 + sRow) * Kb + sCol;
  const int lrow = (l & 15) << 7;
  const int kq0 = (((l >> 4) << 4)) ^ ((l & 7) << 4);
  const int aOff = (wm << 14) + lrow;
  const int bOff = 32768 + ((wn >> 1) << 14) + ((wn & 1) << 13) + lrow;

#define STAGE_H(isB, h, tt) { \
    const int _lo = (((tt) & 1) << 16) + ((isB) << 15) + ((h) << 14); \
    const char* _s = ((isB) ? bS : aS) + ((size_t)((h) << 7)) * Kb + ((size_t)(tt) << 7); \
    load16((const u16*)_s, (u16*)(lds + _lo + sDst)); \
    load16((const u16*)(_s + (Kb << 6)), (u16*)(lds + _lo + 8192 + sDst)); }

#define RD_A(bufb, UQ) \
  _Pragma("unroll") for (int i2 = 0; i2 < 4; ++i2){ \
    aF[i2][0] = *(const bf16x8*)(lds + (bufb) + aOff + ((UQ) << 13) + (i2 << 11) + kq0); \
    aF[i2][1] = *(const bf16x8*)(lds + (bufb) + aOff + ((UQ) << 13) + (i2 << 11) + (kq0 ^ 64)); }

#define RD_B(bufb, VQ) \
  _Pragma("unroll") for (int j2 = 0; j2 < 2; ++j2){ \
    bF[VQ][j2][0] = *(const bf16x8*)(lds + (bufb) + bOff + ((VQ) << 12) + (j2 << 11) + kq0); \
    bF[VQ][j2][1] = *(const bf16x8*)(lds + (bufb) + bOff + ((VQ) << 12) + (j2 << 11) + (kq0 ^ 64)); }

#define MFMA16(UQ, VQ) \
    _Pragma("unroll") for (int i2 = 0; i2 < 4; ++i2) \
      _Pragma("unroll") for (int j2 = 0; j2 < 2; ++j2){ \
        acc[(UQ)*4+i2][(VQ)*2+j2] = __builtin_amdgcn_mfma_f32_16x16x32_bf16(aF[i2][0], bF[VQ][j2][0], acc[(UQ)*4+i2][(VQ)*2+j2], 0, 0, 0); \
        acc[(UQ)*4+i2][(VQ)*2+j2] = __builtin_amdgcn_mfma_f32_16x16x32_bf16(aF[i2][1], bF[VQ][j2][1], acc[(UQ)*4+i2][(VQ)*2+j2], 0, 0, 0); }

#define BAR asm volatile("s_barrier" ::: "memory");
#define VM0 asm volatile("s_waitcnt vmcnt(0)" ::: "memory");

  bf16x8 aF[4][2], bF[2][2][2];
  f32x4 acc[8][4] = {};

  STAGE_H(0,0,0) STAGE_H(1,0,0) STAGE_H(0,1,0) STAGE_H(1,1,0)
  VM0 BAR

#define KTILE(t, bufb) { \
    RD_A(bufb, 0) RD_B(bufb, 0) \
    if ((t) + 1 < NT) { STAGE_H(0,0,(t)+1) STAGE_H(1,0,(t)+1) } \
    MFMA16(0,0) \
    RD_B(bufb, 1) \
    if ((t) + 1 < NT) { STAGE_H(0,1,(t)+1) STAGE_H(1,1,(t)+1) } \
    MFMA16(0,1) \
    RD_A(bufb, 1) \
    MFMA16(1,1) \
    MFMA16(1,0) \
    __builtin_amdgcn_sched_barrier(0); \
    VM0 BAR }

#pragma unroll 1
  for (int tp = 0; tp < NT; tp += 2){
    KTILE(tp, 0)
    KTILE(tp+1, 65536)
  }
#undef KTILE

#pragma unroll
  for (int mf = 0; mf < 8; ++mf){
#pragma unroll
    for (int nf = 0; nf < 4; ++nf){
      const int col = n0 + (wn << 6) + (nf << 4) + (l & 15);
#pragma unroll
      for (int q = 0; q < 4; ++q){
        const int row = m0 + (wm << 7) + (mf << 4) + ((l >> 4) << 2) + q;
        float v = acc[mf][nf][q];
        if (EPI == 0){
          ((float*)Cout)[(size_t)row * N + col] = v + aux[col];
        } else {
          ((u16*)Cout)[((size_t)bz * M + row) * N + col] = f2bf(v);
        }
      }
    }
  }
#undef STAGE_H
#undef RD_A
#undef RD_B
#undef MFMA16
#undef BAR
#undef VM0
}

// gemm256f: round-9 gemm256 with the A-operand read DIRECTLY from f32 x —
// fuses the old conv_bf16(x) pass (192 MiB HBM, ~40 us) into A-staging.
// A path: reg-stage two 16-f32 pairs per tile (issue-early / cvt+ds_write-late,
// ~310-cyc gaps), RNE f2bf (bit-identical to the old conv). B path: unchanged
// global_load_lds. Race discipline = round-9 class: ALL staging writes
// (gload_lds and ds_write) target buffer (t+1)&1 only; tile-end does
// sched_barrier(0) + lgkmcnt(0) [ds_writes drained] + vmcnt(0) [B landed]
// + s_barrier. ds_read->MFMA deps drain reads before the barrier as before.
// f32 out[row*N+col] = acc + bias[col].
__global__ __launch_bounds__(512, 2) void gemm256f(const float* __restrict__ Af, const u16* __restrict__ Bw,
                                                   float* __restrict__ Cout, const float* __restrict__ bias,
                                                   int M, int N, int K){
  __shared__ __align__(16) char lds[131072];
  const char* Bb = (const char*)Bw;
  const int NB = N >> 8;
  const int nwg = gridDim.x;
  const int bid = blockIdx.x;
  const int swzb = (bid & 7) * (nwg >> 3) + (bid >> 3);   // nwg % 8 == 0
  const int m0 = (swzb / NB) << 8;
  const int n0 = (swzb % NB) << 8;
  const int tid = threadIdx.x;
  const int w = tid >> 6, l = tid & 63;
  const int wm = w >> 2, wn = w & 3;
  const size_t Kb = (size_t)K << 1;
  const int NT = K >> 6;
  const int sRow = tid >> 3;
  const int sCol = ((tid & 7) << 4) ^ ((sRow & 7) << 4);   // bf16-byte col (swizzled)
  const int sDst = tid << 4;
  const char* bS = Bb + (size_t)(n0 + sRow) * Kb + sCol;
  const float* aS = Af + (size_t)(m0 + sRow) * K + (sCol >> 1);  // f32-elem col
  const size_t rowK64 = (size_t)64 * K;
  const int lrow = (l & 15) << 7;
  const int kq0 = (((l >> 4) << 4)) ^ ((l & 7) << 4);
  const int aOff = (wm << 14) + lrow;
  const int bOff = 32768 + ((wn >> 1) << 14) + ((wn & 1) << 13) + lrow;

#define STAGE_B(h, tt) { \
    const int _lo = (((tt) & 1) << 16) + 32768 + ((h) << 14); \
    const char* _s = bS + ((size_t)((h) << 7)) * Kb + ((size_t)(tt) << 7); \
    load16((const u16*)_s, (u16*)(lds + _lo + sDst)); \
    load16((const u16*)(_s + (Kb << 6)), (u16*)(lds + _lo + 8192 + sDst)); }

  // pair p covers A chunks 2p,2p+1: rows (2p+c)*64 + sRow, LDS at (2p+c)*8192 + sDst
#define A_ISSUE(p, tt) { \
    const float* _a = aS + (size_t)(tt) * 64 + (size_t)((p) << 1) * rowK64; \
    sa0 = *(const float4*)(_a);           sb0 = *(const float4*)(_a + 4); \
    sa1 = *(const float4*)(_a + rowK64);  sb1 = *(const float4*)(_a + rowK64 + 4); }
#define A_WRITE(p, tt) { \
    const int _lo = (((tt) & 1) << 16) + ((p) << 14); \
    u16x8 o0 = { f2bf(sa0.x), f2bf(sa0.y), f2bf(sa0.z), f2bf(sa0.w), \
                 f2bf(sb0.x), f2bf(sb0.y), f2bf(sb0.z), f2bf(sb0.w) }; \
    *(u16x8*)(lds + _lo + sDst) = o0; \
    u16x8 o1 = { f2bf(sa1.x), f2bf(sa1.y), f2bf(sa1.z), f2bf(sa1.w), \
                 f2bf(sb1.x), f2bf(sb1.y), f2bf(sb1.z), f2bf(sb1.w) }; \
    *(u16x8*)(lds + _lo + 8192 + sDst) = o1; }

#define RD_A(bufb, UQ) \
  _Pragma("unroll") for (int i2 = 0; i2 < 4; ++i2){ \
    aF[i2][0] = *(const bf16x8*)(lds + (bufb) + aOff + ((UQ) << 13) + (i2 << 11) + kq0); \
    aF[i2][1] = *(const bf16x8*)(lds + (bufb) + aOff + ((UQ) << 13) + (i2 << 11) + (kq0 ^ 64)); }

#define RD_B(bufb, VQ) \
  _Pragma("unroll") for (int j2 = 0; j2 < 2; ++j2){ \
    bF[VQ][j2][0] = *(const bf16x8*)(lds + (bufb) + bOff + ((VQ) << 12) + (j2 << 11) + kq0); \
    bF[VQ][j2][1] = *(const bf16x8*)(lds + (bufb) + bOff + ((VQ) << 12) + (j2 << 11) + (kq0 ^ 64)); }

#define MFMA16(UQ, VQ) \
    _Pragma("unroll") for (int i2 = 0; i2 < 4; ++i2) \
      _Pragma("unroll") for (int j2 = 0; j2 < 2; ++j2){ \
        acc[(UQ)*4+i2][(VQ)*2+j2] = __builtin_amdgcn_mfma_f32_16x16x32_bf16(aF[i2][0], bF[VQ][j2][0], acc[(UQ)*4+i2][(VQ)*2+j2], 0, 0, 0); \
        acc[(UQ)*4+i2][(VQ)*2+j2] = __builtin_amdgcn_mfma_f32_16x16x32_bf16(aF[i2][1], bF[VQ][j2][1], acc[(UQ)*4+i2][(VQ)*2+j2], 0, 0, 0); }

#define BAR asm volatile("s_barrier" ::: "memory");
#define LGK0 asm volatile("s_waitcnt lgkmcnt(0)" ::: "memory");
#define VM0 asm volatile("s_waitcnt vmcnt(0)" ::: "memory");

  bf16x8 aF[4][2], bF[2][2][2];
  float4 sa0, sb0, sa1, sb1;
  f32x4 acc[8][4] = {};

  // prologue: stage tile 0 (A via reg+cvt, B via load_lds) into buf 0
  A_ISSUE(0, 0) STAGE_B(0, 0) STAGE_B(1, 0)
  A_WRITE(0, 0)
  A_ISSUE(1, 0)
  A_WRITE(1, 0)
  LGK0 VM0 BAR

#define KTILE(t, bufb) { \
    if ((t) + 1 < NT) { A_ISSUE(0, (t)+1) STAGE_B(0, (t)+1) } \
    RD_A(bufb, 0) RD_B(bufb, 0) \
    MFMA16(0,0) \
    RD_B(bufb, 1) \
    if ((t) + 1 < NT) { STAGE_B(1, (t)+1) } \
    MFMA16(0,1) \
    if ((t) + 1 < NT) { A_WRITE(0, (t)+1) A_ISSUE(1, (t)+1) } \
    RD_A(bufb, 1) \
    MFMA16(1,1) \
    MFMA16(1,0) \
    if ((t) + 1 < NT) { A_WRITE(1, (t)+1) } \
    __builtin_amdgcn_sched_barrier(0); \
    LGK0 VM0 BAR }

#pragma unroll 1
  for (int tp = 0; tp < NT; tp += 2){
    KTILE(tp, 0)
    KTILE(tp+1, 65536)
  }
#undef KTILE

#pragma unroll
  for (int mf = 0; mf < 8; ++mf){
#pragma unroll
    for (int nf = 0; nf < 4; ++nf){
      const int col = n0 + (wn << 6) + (nf << 4) + (l & 15);
#pragma unroll
      for (int q = 0; q < 4; ++q){
        const int row = m0 + (wm << 7) + (mf << 4) + ((l >> 4) << 2) + q;
        Cout[(size_t)row * N + col] = acc[mf][nf][q] + bias[col];
      }
    }
  }
#undef STAGE_B
#undef A_ISSUE
#undef A_WRITE
#undef RD_A
#undef RD_B
#undef MFMA16
#undef BAR
#undef LGK0
#undef VM0
}

extern "C" void kernel_launch(void* const* d_in, const int* in_sizes, int n_in,
                              void* d_out, int out_size, void* d_ws, size_t ws_size,
                              hipStream_t stream){
  const float* W    = (const float*)d_in[0];
  const float* bias = (const float*)d_in[1];
  const float* x    = (const float*)d_in[2];
  const float* R    = (const float*)d_in[3];
  (void)in_sizes; (void)n_in; (void)out_size; (void)ws_size;

  char* ws = (char*)d_ws;
  const size_t MiB = (size_t)1 << 20;
  u16*   Sbf  = (u16*)(ws + 0 * MiB);    // 4 MiB ; reused as G
  u16*   Dbf  = (u16*)(ws + 4 * MiB);    // 4 MiB
  u16*   X1   = (u16*)(ws + 16 * MiB);   // 4 MiB
  u16*   Ybf  = (u16*)(ws + 20 * MiB);   // 4 MiB
  u16*   X2   = (u16*)(ws + 24 * MiB);   // 4 MiB
  u16*   Phl  = (u16*)(ws + 28 * MiB);   // 8 MiB  [Ph | Pl] width-1024
  u16*   X1d  = (u16*)(ws + 44 * MiB);   // 8 MiB  [X1 | X1] width-1024
  u16*   G    = Sbf;
  u16*   Wt   = (u16*)(ws + 8 * MiB);    // 32 MiB [8,40) — NS temps there dead by then
  u16*   filt = (u16*)(ws + 64 * MiB);   // 32 MiB [64,96)

  const dim3 gNS(8, 8, 8);   // 512 blocks: 64x64 tiles, 2 blocks/CU (gemm_ns)

  // Phase 1: S (bf16) and D = (c+1)(cI - S)
  build_s<<<8192, 256, 0, stream>>>(R, Sbf, Dbf);
  // Phase 2: P = c^2 I + S S^T ; fused epilogue emits Phl=[Ph|Pl], X1, X1d
  gemm_ns<11><<<gNS, 256, 0, stream>>>(Sbf, Sbf, Phl, X1, X1d, 512, 512, 512);
  // Phase 3: Y = 2I - (Ph+Pl) X1   (one K=1024 gemm, full-precision P)
  gemm_ns<3><<<gNS, 256, 0, stream>>>(Phl, X1d, Ybf, nullptr, nullptr, 512, 512, 1024);
  // Phase 4: X2 = X1 Y
  gemm_ns<2><<<gNS, 256, 0, stream>>>(X1, Ybf, X2, nullptr, nullptr, 512, 512, 512);
  // Phase 5: G = Q = D X2 - I
  gemm_ns<9><<<gNS, 256, 0, stream>>>(Dbf, X2, G, nullptr, nullptr, 512, 512, 512);
  // Phase 6: filt = G @ Wb (bf16)
  transpose_w<<<dim3(128, 16, 8), 256, 0, stream>>>(W, Wt);
  gemm256<2><<<dim3(32, 1, 8), 512, 0, stream>>>(G, Wt, (void*)filt, nullptr, 512, 4096, 512);
  // Phase 7: out = x @ filt^T + bias  (A read directly from f32 x; conv pass fused)
  gemm256f<<<dim3(512, 1, 1), 512, 0, stream>>>(x, filt, (float*)d_out, bias, 8192, 4096, 4096);
}